// Round 7
// baseline (269.530 us; speedup 1.0000x reference)
//
#include <hip/hip_runtime.h>
#include <math.h>

#define Dd 160
#define Hh 160
#define Ww 160
#define TW 32
#define TH 28                 // output rows per tile; 6 tiles, last masked
#define NHT 6
#define DCHUNK 10
#define NSLICE (DCHUNK + 4)   // 14
#define NDC (Dd / DCHUNK)     // 16
#define NT 512
#define NCH 5
#define HR 32                 // halo rows = TH + 4  (power of two!)
#define PDIM 36               // per-w row stride: 16B-aligned, C b128 word-uniform
#define SLICE (Hh * Ww)

__global__ void lncc_zero(float* out) { out[0] = 0.0f; }

// Drain LDS ops only; global prefetch loads stay in flight across the barrier.
__device__ __forceinline__ void bar_lgkm() {
    asm volatile("s_waitcnt lgkmcnt(0)" ::: "memory");
    __builtin_amdgcn_s_barrier();
    asm volatile("" ::: "memory");
}

__global__ __launch_bounds__(NT, 4)
void lncc_main(const float* __restrict__ M, const float* __restrict__ R,
               const float* __restrict__ kern, float* __restrict__ out)
{
    // Double-buffered W-sum planes: sw[par][ch][w][row]  (46080 B)
    __shared__ float sw[2][NCH][TW][PDIM];
    __shared__ float red[NT / 64];

    const int tid = threadIdx.x;
    const int w0 = blockIdx.x * TW;
    const int h0 = blockIdx.y * TH;
    const int b  = blockIdx.z >> 4;               // NDC = 16
    const int d0 = (blockIdx.z & 15) * DCHUNK;
    const float k0 = kern[0];                     // 1/125

    const bool isB = tid >= 256;                  // waves 4-7: producer
    const bool isC = tid < 256;                   // waves 0-3: consumer

    // ================= B-role (tid 256..511) =================
    // Lane labeling chosen so each wave spans (row 0..15|16..31) x (g-parity 0,1)
    // -> scalar-write banks 2-way (free):  bank = 16(g&1) + 4j + row  hits 32 banks.
    const int bt  = tid - 256;
    const int row = (bt & 15) | ((bt & 64) >> 2);           // 0..31
    const int g   = ((bt >> 4) & 3) | ((bt & 128) >> 5);    // 0..7
    const int gh  = h0 + row - 2;
    const bool hok = isB && gh >= 0 && gh < Hh;
    bool qok[3]; int qoff[3];
#pragma unroll
    for (int k = 0; k < 3; ++k) {
        int gw = w0 - 4 + 4 * (g + k);            // aligned quads, fully in or out
        qok[k]  = hok && gw >= 0 && gw <= Ww - 4;
        qoff[k] = gh * Ww + gw;
    }
    const size_t bb = (size_t)b * Dd * SLICE;
    const float* Mb = M + bb;
    const float* Rb = R + bb;

    float4 cm[2][3], cr[2][3];                    // depth-2 prefetch (B-only regs)
    auto issue = [&](int s, int pp) {
        if (!isB) return;
        int dd = d0 - 2 + s;
        bool dok = dd >= 0 && dd < Dd;
        const float* Ms = Mb + (size_t)(dok ? dd : 0) * SLICE;
        const float* Rs = Rb + (size_t)(dok ? dd : 0) * SLICE;
#pragma unroll
        for (int k = 0; k < 3; ++k) {
            bool ok = dok && qok[k];
            cm[pp][k] = ok ? *(const float4*)(Ms + qoff[k]) : make_float4(0.f, 0.f, 0.f, 0.f);
            cr[pp][k] = ok ? *(const float4*)(Rs + qoff[k]) : make_float4(0.f, 0.f, 0.f, 0.f);
        }
    };

    auto bphase = [&](int sp) {
        if (!isB) return;
        float am[12], ar[12];
        *(float4*)&am[0] = cm[sp][0]; *(float4*)&am[4] = cm[sp][1]; *(float4*)&am[8] = cm[sp][2];
        *(float4*)&ar[0] = cr[sp][0]; *(float4*)&ar[4] = cr[sp][1]; *(float4*)&ar[8] = cr[sp][2];
        float mm[8], rr[8], mr[8];
#pragma unroll
        for (int k2 = 0; k2 < 8; ++k2) {
            float a = am[k2 + 2], r_ = ar[k2 + 2];
            mm[k2] = a * a; rr[k2] = r_ * r_; mr[k2] = a * r_;
        }
        float sm  = am[2] + am[3] + am[4] + am[5] + am[6];
        float sr_ = ar[2] + ar[3] + ar[4] + ar[5] + ar[6];
        float smm = mm[0] + mm[1] + mm[2] + mm[3] + mm[4];
        float srr = rr[0] + rr[1] + rr[2] + rr[3] + rr[4];
        float smr = mr[0] + mr[1] + mr[2] + mr[3] + mr[4];
#pragma unroll
        for (int j = 0; j < 4; ++j) {
            if (j) {
                sm  += am[j + 6] - am[j + 1];
                sr_ += ar[j + 6] - ar[j + 1];
                smm += mm[j + 4] - mm[j - 1];
                srr += rr[j + 4] - rr[j - 1];
                smr += mr[j + 4] - mr[j - 1];
            }
            const int wq = 4 * g + j;
            sw[sp][0][wq][row] = sm;
            sw[sp][1][wq][row] = sr_;
            sw[sp][2][wq][row] = smm;
            sw[sp][3][wq][row] = srr;
            sw[sp][4][wq][row] = smr;
        }
    };

    // ================= C-role (tid 0..255) =================
    const int cw = tid & 31;
    const int hg = tid >> 5;                      // 0..7; hg==7 idle (28/4 = 7 groups)
    const bool cact = isC && hg < 7;

    float ring[5][NCH][4];
#pragma unroll
    for (int t = 0; t < 5; ++t)
#pragma unroll
        for (int c = 0; c < NCH; ++c)
#pragma unroll
            for (int j = 0; j < 4; ++j) ring[t][c][j] = 0.f;
    float acc = 0.f;

    auto cphase = [&](int cs, int cp, int slot) {
        if (!cact) return;
        const float* base = &sw[cp][0][cw][4 * hg];
#pragma unroll
        for (int c = 0; c < NCH; ++c) {
            float4 A  = *(const float4*)(base + c * TW * PDIM);
            float4 Bq = *(const float4*)(base + c * TW * PDIM + 4);
            float t0 = A.x + A.y + A.z + A.w + Bq.x;
            float t1 = t0 + Bq.y - A.x;
            float t2 = t1 + Bq.z - A.y;
            float t3 = t2 + Bq.w - A.z;
            ring[slot][c][0] = t0;
            ring[slot][c][1] = t1;
            ring[slot][c][2] = t2;
            ring[slot][c][3] = t3;
        }
        if (cs >= 4) {
#pragma unroll
            for (int j = 0; j < 4; ++j) {
                if (h0 + 4 * hg + j < Hh) {       // tail-tile mask (by==5)
                    float S[NCH];
#pragma unroll
                    for (int c = 0; c < NCH; ++c)
                        S[c] = ring[0][c][j] + ring[1][c][j] + ring[2][c][j]
                             + ring[3][c][j] + ring[4][c][j];
                    float Mm  = S[0] * k0, Rm = S[1] * k0;
                    float MMm = S[2] * k0, RRm = S[3] * k0, MRm = S[4] * k0;
                    float Mv = sqrtf(MMm - Mm * Mm + 1e-5f);
                    float Rv = sqrtf(RRm - Rm * Rm + 1e-5f);
                    acc += (MRm - Mm * Rm) / (Mv * Rv + 1e-5f);
                }
            }
        }
    };

    // ================= schedule: phase k runs B(k) || C(k-1), one barrier/phase ====
    issue(0, 0);
    issue(1, 1);
#pragma unroll
    for (int k = 0; k <= NSLICE; ++k) {           // 15 phases, fully unrolled
        if (k) bar_lgkm();
        if (k < NSLICE) {
            bphase(k & 1);                        // write buf[k&1] (pf parity k&1)
            if (k + 2 < NSLICE) issue(k + 2, k & 1);
        }
        if (k >= 1) cphase(k - 1, (k - 1) & 1, (k - 1) % 5);
    }

    // ================= reduction -> one atomic =================
#pragma unroll
    for (int off = 32; off; off >>= 1) acc += __shfl_down(acc, off, 64);
    if ((tid & 63) == 0) red[tid >> 6] = acc;
    __syncthreads();
    if (tid == 0) {
        float t = 0.f;
#pragma unroll
        for (int i = 0; i < NT / 64; ++i) t += red[i];
        atomicAdd(out, -t * (1.0f / 8192000.0f)); // mean over 2*160^3, negated
    }
}

extern "C" void kernel_launch(void* const* d_in, const int* in_sizes, int n_in,
                              void* d_out, int out_size, void* d_ws, size_t ws_size,
                              hipStream_t stream) {
    const float* M = (const float*)d_in[0];
    const float* R = (const float*)d_in[1];
    const float* K = (const float*)d_in[2];
    float* out = (float*)d_out;

    lncc_zero<<<1, 1, 0, stream>>>(out);

    dim3 grid(Ww / TW, NHT, 2 * NDC);             // (5, 6, 32) = 960 blocks
    lncc_main<<<grid, NT, 0, stream>>>(M, R, K, out);
}

// Round 8
// 159.251 us; speedup vs baseline: 1.6925x; 1.6925x over previous
//
#include <hip/hip_runtime.h>
#include <math.h>

#define Dd 160
#define Hh 160
#define Ww 160
#define TW 32
#define TH 32
#define DCHUNK 10
#define NT 320
#define NCH 5
#define PDIM 36               // [ch][w][row] stride: 144B (16B-aligned); C b128 bank-uniform
#define NSLICE (DCHUNK + 4)   // 14
#define NDC (Dd / DCHUNK)     // 16
#define SLICE (Hh * Ww)

__global__ void lncc_zero(float* out) { out[0] = 0.0f; }

// Barrier draining LDS ops only — global prefetch loads stay in flight across it.
__device__ __forceinline__ void bar_lgkm() {
    asm volatile("s_waitcnt lgkmcnt(0)" ::: "memory");
    __builtin_amdgcn_s_barrier();
    asm volatile("" ::: "memory");
}

__global__ __launch_bounds__(NT, 2)
void lncc_main(const float* __restrict__ M,
               const float* __restrict__ R,
               const float* __restrict__ kern,
               float* __restrict__ out)
{
    // W-sums, h-contiguous: sw[ch][w][row].  5*32*36*4 = 23040 B -> 6 blocks LDS-capable.
    __shared__ float sw[NCH][TW][PDIM];
    __shared__ float red[NT / 64];

    const int tid = threadIdx.x;
    const int w0 = blockIdx.x * TW;
    const int h0 = blockIdx.y * TH;
    const int b  = blockIdx.z >> 4;              // NDC = 16
    const int d0 = (blockIdx.z & 15) * DCHUNK;

    const float k0 = kern[0];                    // 1/125

    // ---------------- B-role: W-sums from global (register sliding window) ----------------
    const bool isB = tid < (TH + 4) * 8;         // 288 threads: 36 halo rows x 8 w-quads
    const int  g   = tid & 7;
    const int  row = tid >> 3;                   // 0..39 (valid < 36)
    const int  gh  = h0 + row - 2;
    const bool hok = isB && gh >= 0 && gh < Hh;
    bool qok[3]; int qoff[3];
#pragma unroll
    for (int k = 0; k < 3; ++k) {
        int gw = w0 - 4 + 4 * (g + k);           // aligned quads, fully in or out
        qok[k]  = hok && gw >= 0 && gw <= (Ww - 4);
        qoff[k] = gh * Ww + gw;
    }
    const size_t bbase = (size_t)b * Dd * SLICE;
    const float* Mb = M + bbase;
    const float* Rb = R + bbase;

    float4 cm[3], cr[3];                         // depth-1 prefetch
    auto issue = [&](int s) {
        int dd = d0 - 2 + s;
        bool dok = dd >= 0 && dd < Dd;
        const float* Ms = Mb + (size_t)(dok ? dd : 0) * SLICE;
        const float* Rs = Rb + (size_t)(dok ? dd : 0) * SLICE;
#pragma unroll
        for (int k = 0; k < 3; ++k) {
            bool ok = dok && qok[k];
            cm[k] = ok ? *(const float4*)(Ms + qoff[k]) : make_float4(0.f, 0.f, 0.f, 0.f);
            cr[k] = ok ? *(const float4*)(Rs + qoff[k]) : make_float4(0.f, 0.f, 0.f, 0.f);
        }
    };
    // write base: &sw[0][4g][row]; (c,j) folded into offsets (w-stride = PDIM)
    float* swp = &sw[0][g * 4][row];

    // ---------------- C-role: H-sums via b128, running D-window ----------------
    const bool isC = tid < 256;
    const int  cw  = tid & 31;
    const int  hg  = (tid >> 5) & 7;             // 4-row output group
    const float* crd = &sw[0][cw][4 * hg];       // b128 bank-uniform at stride 36

    float S[NCH][4];
    float ring[5][NCH][4];
#pragma unroll
    for (int c = 0; c < NCH; ++c)
#pragma unroll
        for (int j = 0; j < 4; ++j) {
            S[c][j] = 0.f;
#pragma unroll
            for (int t = 0; t < 5; ++t) ring[t][c][j] = 0.f;
        }

    float acc = 0.f;
    issue(0);

    for (int s5 = 0; s5 < 15; s5 += 5) {
#pragma unroll
        for (int so = 0; so < 5; ++so) {
            const int s = s5 + so;               // slot = so (static); s % 5 == so
            if (s >= NSLICE) break;

            bar_lgkm();                          // sw free: previous C done reading

            if (isB) {
                float am[12], ar[12];
                *(float4*)&am[0] = cm[0]; *(float4*)&am[4] = cm[1]; *(float4*)&am[8] = cm[2];
                *(float4*)&ar[0] = cr[0]; *(float4*)&ar[4] = cr[1]; *(float4*)&ar[8] = cr[2];
                float mm[8], rr[8], mr[8];
#pragma unroll
                for (int k = 0; k < 8; ++k) {
                    float a = am[k + 2], r_ = ar[k + 2];
                    mm[k] = a * a; rr[k] = r_ * r_; mr[k] = a * r_;
                }
                float sm  = am[2] + am[3] + am[4] + am[5] + am[6];
                float sr_ = ar[2] + ar[3] + ar[4] + ar[5] + ar[6];
                float smm = mm[0] + mm[1] + mm[2] + mm[3] + mm[4];
                float srr = rr[0] + rr[1] + rr[2] + rr[3] + rr[4];
                float smr = mr[0] + mr[1] + mr[2] + mr[3] + mr[4];
#pragma unroll
                for (int j = 0; j < 4; ++j) {
                    if (j) {
                        sm  += am[j + 6] - am[j + 1];
                        sr_ += ar[j + 6] - ar[j + 1];
                        smm += mm[j + 4] - mm[j - 1];
                        srr += rr[j + 4] - rr[j - 1];
                        smr += mr[j + 4] - mr[j - 1];
                    }
                    float* wp = swp + j * PDIM;
                    wp[0 * TW * PDIM] = sm;
                    wp[1 * TW * PDIM] = sr_;
                    wp[2 * TW * PDIM] = smm;
                    wp[3 * TW * PDIM] = srr;
                    wp[4 * TW * PDIM] = smr;
                }
                if (s + 1 < NSLICE) issue(s + 1);   // regs free now; flies across barriers
            }

            bar_lgkm();                          // sw published

            if (isC) {
#pragma unroll
                for (int c = 0; c < NCH; ++c) {
                    float4 A  = *(const float4*)(crd + c * TW * PDIM);
                    float4 Bq = *(const float4*)(crd + c * TW * PDIM + 4);
                    float t0 = A.x + A.y + A.z + A.w + Bq.x;
                    float t1 = t0 + Bq.y - A.x;
                    float t2 = t1 + Bq.z - A.y;
                    float t3 = t2 + Bq.w - A.z;
                    S[c][0] += t0 - ring[so][c][0]; ring[so][c][0] = t0;
                    S[c][1] += t1 - ring[so][c][1]; ring[so][c][1] = t1;
                    S[c][2] += t2 - ring[so][c][2]; ring[so][c][2] = t2;
                    S[c][3] += t3 - ring[so][c][3]; ring[so][c][3] = t3;
                }
                if (s >= 4) {
#pragma unroll
                    for (int j = 0; j < 4; ++j) {
                        float Mm  = S[0][j] * k0, Rm = S[1][j] * k0;
                        float MMm = S[2][j] * k0, RRm = S[3][j] * k0, MRm = S[4][j] * k0;
                        float Mv = sqrtf(MMm - Mm * Mm + 1e-5f);
                        float Rv = sqrtf(RRm - Rm * Rm + 1e-5f);
                        acc += (MRm - Mm * Rm) / (Mv * Rv + 1e-5f);
                    }
                }
            }
        }
    }

    // ---------------- reduction -> one atomic ----------------
#pragma unroll
    for (int off = 32; off; off >>= 1) acc += __shfl_down(acc, off, 64);
    if ((tid & 63) == 0) red[tid >> 6] = acc;
    __syncthreads();
    if (tid == 0) {
        float t = red[0] + red[1] + red[2] + red[3] + red[4];
        atomicAdd(out, -t * (1.0f / 8192000.0f));   // mean over 2*160^3, negated
    }
}

extern "C" void kernel_launch(void* const* d_in, const int* in_sizes, int n_in,
                              void* d_out, int out_size, void* d_ws, size_t ws_size,
                              hipStream_t stream) {
    const float* M = (const float*)d_in[0];
    const float* R = (const float*)d_in[1];
    const float* K = (const float*)d_in[2];
    float* out = (float*)d_out;

    lncc_zero<<<1, 1, 0, stream>>>(out);

    dim3 grid(Ww / TW, Hh / TH, 2 * NDC);        // (5, 5, 32) = 800 blocks
    lncc_main<<<grid, NT, 0, stream>>>(M, R, K, out);
}